// Round 1
// baseline (1610.527 us; speedup 1.0000x reference)
//
#include <hip/hip_runtime.h>

#define E_DIM 1024
#define TM 128
#define TN 128
#define TK 16

// ---- monotone float<->uint encoding so unsigned atomicMin == float min ----
__device__ __forceinline__ unsigned f2mono(float f) {
  unsigned u = __float_as_uint(f);
  return (u & 0x80000000u) ? ~u : (u | 0x80000000u);
}
__device__ __forceinline__ float mono2f(unsigned u) {
  return __uint_as_float((u & 0x80000000u) ? (u ^ 0x80000000u) : ~u);
}

// Kernel 1: per-row inverse norms of anchor/positive, ap_i = cos(a_i, p_i),
// and init of the per-row running-min array.
__global__ __launch_bounds__(256) void norms_kernel(
    const float* __restrict__ A, const float* __restrict__ P,
    float* __restrict__ inv_na, float* __restrict__ inv_np,
    float* __restrict__ ap, unsigned* __restrict__ min_bits) {
  const int row = blockIdx.x;
  const int t = threadIdx.x;
  const float4* a4 = (const float4*)(A + (size_t)row * E_DIM);
  const float4* p4 = (const float4*)(P + (size_t)row * E_DIM);
  float sa = 0.f, sp = 0.f, sab = 0.f;
  for (int c = t; c < E_DIM / 4; c += 256) {
    float4 a = a4[c];
    float4 p = p4[c];
    sa  += a.x * a.x + a.y * a.y + a.z * a.z + a.w * a.w;
    sp  += p.x * p.x + p.y * p.y + p.z * p.z + p.w * p.w;
    sab += a.x * p.x + a.y * p.y + a.z * p.z + a.w * p.w;
  }
#pragma unroll
  for (int off = 32; off > 0; off >>= 1) {
    sa  += __shfl_down(sa, off);
    sp  += __shfl_down(sp, off);
    sab += __shfl_down(sab, off);
  }
  __shared__ float red[4][3];
  const int wave = t >> 6, lane = t & 63;
  if (lane == 0) { red[wave][0] = sa; red[wave][1] = sp; red[wave][2] = sab; }
  __syncthreads();
  if (t == 0) {
    sa  = red[0][0] + red[1][0] + red[2][0] + red[3][0];
    sp  = red[0][1] + red[1][1] + red[2][1] + red[3][1];
    sab = red[0][2] + red[1][2] + red[2][2] + red[3][2];
    float ina = 1.0f / sqrtf(sa);
    float inp = 1.0f / sqrtf(sp);
    inv_na[row] = ina;
    inv_np[row] = inp;
    ap[row] = sab * ina * inp;
    min_bits[row] = 0xFFFFFFFFu;  // +max in monotone encoding
  }
}

// Kernel 2: tiled fp32 "GEMM" C = A P^T with fused per-row scaling by inverse
// norms and per-row min over j != i. 128x128 tile, 256 threads, 8x8 acc/thread.
__global__ __launch_bounds__(256) void simmin_kernel(
    const float* __restrict__ A, const float* __restrict__ P,
    const float* __restrict__ inv_na, const float* __restrict__ inv_np,
    unsigned* __restrict__ min_bits) {
  __shared__ float As[TK][TM + 4];  // K-outer, +4 pad: float4 reads stay aligned,
  __shared__ float Ps[TK][TN + 4];  // transpose-store aliasing is 2-way (free)

  const int tid = threadIdx.x;
  const int rowBase = blockIdx.y * TM;
  const int colBase = blockIdx.x * TN;
  const int tx = tid & 15;   // 16 col-groups
  const int ty = tid >> 4;   // 16 row-groups

  float acc[8][8];
#pragma unroll
  for (int i = 0; i < 8; ++i)
#pragma unroll
    for (int j = 0; j < 8; ++j) acc[i][j] = 0.f;

  const int m0 = tid >> 2;       // 0..63 (row within tile, chunk mapping)
  const int kc = tid & 3;        // 0..3  (which float4 along K)

  for (int kt = 0; kt < E_DIM; kt += TK) {
#pragma unroll
    for (int r = 0; r < 2; ++r) {
      const int m = m0 + r * 64;
      float4 av = *(const float4*)(A + (size_t)(rowBase + m) * E_DIM + kt + kc * 4);
      float4 pv = *(const float4*)(P + (size_t)(colBase + m) * E_DIM + kt + kc * 4);
      As[kc * 4 + 0][m] = av.x; As[kc * 4 + 1][m] = av.y;
      As[kc * 4 + 2][m] = av.z; As[kc * 4 + 3][m] = av.w;
      Ps[kc * 4 + 0][m] = pv.x; Ps[kc * 4 + 1][m] = pv.y;
      Ps[kc * 4 + 2][m] = pv.z; Ps[kc * 4 + 3][m] = pv.w;
    }
    __syncthreads();
#pragma unroll
    for (int k = 0; k < TK; ++k) {
      float4 a0 = *(const float4*)&As[k][ty * 8];
      float4 a1 = *(const float4*)&As[k][ty * 8 + 4];
      float4 b0 = *(const float4*)&Ps[k][tx * 8];
      float4 b1 = *(const float4*)&Ps[k][tx * 8 + 4];
      float a[8] = {a0.x, a0.y, a0.z, a0.w, a1.x, a1.y, a1.z, a1.w};
      float b[8] = {b0.x, b0.y, b0.z, b0.w, b1.x, b1.y, b1.z, b1.w};
#pragma unroll
      for (int i = 0; i < 8; ++i)
#pragma unroll
        for (int j = 0; j < 8; ++j) acc[i][j] = fmaf(a[i], b[j], acc[i][j]);
    }
    __syncthreads();
  }

  // Epilogue: scale to cosine, per-row min excluding the diagonal.
  float ina[8], inp[8];
#pragma unroll
  for (int i = 0; i < 8; ++i) ina[i] = inv_na[rowBase + ty * 8 + i];
#pragma unroll
  for (int j = 0; j < 8; ++j) inp[j] = inv_np[colBase + tx * 8 + j];

#pragma unroll
  for (int i = 0; i < 8; ++i) {
    const int gi = rowBase + ty * 8 + i;
    float v = 3.4e38f;
#pragma unroll
    for (int j = 0; j < 8; ++j) {
      const int gj = colBase + tx * 8 + j;
      float s = acc[i][j] * ina[i] * inp[j];
      if (gj != gi) v = fminf(v, s);
    }
    // min across the 16 tx lanes (same ty => contiguous lanes in a wave)
#pragma unroll
    for (int off = 1; off < 16; off <<= 1) v = fminf(v, __shfl_xor(v, off));
    if (tx == 0) atomicMin(&min_bits[gi], f2mono(v));
  }
}

// Kernel 3: loss_i = relu(1 + ap_i - an_i); out = mean(loss). Single block.
__global__ __launch_bounds__(256) void loss_kernel(
    const float* __restrict__ ap, const unsigned* __restrict__ min_bits,
    float* __restrict__ out, int B) {
  const int t = threadIdx.x;
  float s = 0.f;
  for (int i = t; i < B; i += 256) {
    float an = mono2f(min_bits[i]);
    float l = 1.0f + ap[i] - an;
    s += (l > 0.f) ? l : 0.f;
  }
#pragma unroll
  for (int off = 32; off > 0; off >>= 1) s += __shfl_down(s, off);
  __shared__ float red[4];
  const int wave = t >> 6, lane = t & 63;
  if (lane == 0) red[wave] = s;
  __syncthreads();
  if (t == 0) out[0] = (red[0] + red[1] + red[2] + red[3]) / (float)B;
}

extern "C" void kernel_launch(void* const* d_in, const int* in_sizes, int n_in,
                              void* d_out, int out_size, void* d_ws, size_t ws_size,
                              hipStream_t stream) {
  const float* A = (const float*)d_in[0];  // anchor  [B][1024] fp32
  const float* P = (const float*)d_in[1];  // positive[B][1024] fp32
  const int B = in_sizes[0] / E_DIM;       // 8192

  // workspace: inv_na[B] | inv_np[B] | ap[B] | min_bits[B]  (= 128 KB @ B=8192)
  float* inv_na = (float*)d_ws;
  float* inv_np = inv_na + B;
  float* ap = inv_np + B;
  unsigned* min_bits = (unsigned*)(ap + B);

  norms_kernel<<<B, 256, 0, stream>>>(A, P, inv_na, inv_np, ap, min_bits);
  dim3 grid(B / TN, B / TM);
  simmin_kernel<<<grid, 256, 0, stream>>>(A, P, inv_na, inv_np, min_bits);
  loss_kernel<<<1, 256, 0, stream>>>(ap, min_bits, (float*)d_out, B);
}

// Round 3
// 423.643 us; speedup vs baseline: 3.8016x; 3.8016x over previous
//
#include <hip/hip_runtime.h>

#define E_DIM 1024
#define BK 32

typedef __attribute__((ext_vector_type(8))) short bf16x8;
typedef __attribute__((ext_vector_type(4))) float f32x4;

// ---- monotone float->uint so unsigned min == float min ----
__device__ __forceinline__ unsigned f2mono(float f) {
  unsigned u = __float_as_uint(f);
  return (u & 0x80000000u) ? ~u : (u | 0x80000000u);
}
// pack two fp32 into bf16x2 (truncation) with one v_perm_b32
__device__ __forceinline__ unsigned pk_bf16(float lo, float hi) {
  return __builtin_amdgcn_perm(__float_as_uint(hi), __float_as_uint(lo), 0x07060302u);
}

// Kernel 1: per-row inverse norms, exact ap_i, init packed min array.
__global__ __launch_bounds__(256) void norms_kernel(
    const float* __restrict__ A, const float* __restrict__ P,
    float* __restrict__ inv_na, float* __restrict__ inv_np,
    float* __restrict__ ap, unsigned long long* __restrict__ min64) {
  const int row = blockIdx.x;
  const int t = threadIdx.x;
  const float4* a4 = (const float4*)(A + (size_t)row * E_DIM);
  const float4* p4 = (const float4*)(P + (size_t)row * E_DIM);
  float sa = 0.f, sp = 0.f, sab = 0.f;
  for (int c = t; c < E_DIM / 4; c += 256) {
    float4 a = a4[c];
    float4 p = p4[c];
    sa  += a.x * a.x + a.y * a.y + a.z * a.z + a.w * a.w;
    sp  += p.x * p.x + p.y * p.y + p.z * p.z + p.w * p.w;
    sab += a.x * p.x + a.y * p.y + a.z * p.z + a.w * p.w;
  }
#pragma unroll
  for (int off = 32; off > 0; off >>= 1) {
    sa  += __shfl_down(sa, off);
    sp  += __shfl_down(sp, off);
    sab += __shfl_down(sab, off);
  }
  __shared__ float red[4][3];
  const int wave = t >> 6, lane = t & 63;
  if (lane == 0) { red[wave][0] = sa; red[wave][1] = sp; red[wave][2] = sab; }
  __syncthreads();
  if (t == 0) {
    sa  = red[0][0] + red[1][0] + red[2][0] + red[3][0];
    sp  = red[0][1] + red[1][1] + red[2][1] + red[3][1];
    sab = red[0][2] + red[1][2] + red[2][2] + red[3][2];
    float ina = 1.0f / sqrtf(sa);
    float inp = 1.0f / sqrtf(sp);
    inv_na[row] = ina;
    inv_np[row] = inp;
    ap[row] = sab * ina * inp;
    min64[row] = 0xFFFFFFFFFFFFFFFFULL;  // +max packed
  }
}

// Kernel 2: bf16 MFMA GEMM  dot = A P^T  (128x128 tile, 4 waves, 4x4 16x16x32
// tiles/wave), fused per-row min+argmin of dot*inv_np[col], j != i.
// Row scale inv_na>0 dropped: it can't change the argmin; value repaired later
// by an exact fp32 re-dot of the selected pair (an_kernel).
__global__ __launch_bounds__(256) void simmin_mfma(
    const float* __restrict__ A, const float* __restrict__ P,
    const float* __restrict__ inv_np, unsigned long long* __restrict__ min64) {
  // stride 40 bf16 (80B) per row: 16B-aligned b128 frags, 2-way bank alias (free)
  __shared__ __align__(16) short As[128 * 40];
  __shared__ __align__(16) short Ps[128 * 40];

  const int tid = threadIdx.x;
  const int wave = tid >> 6, lane = tid & 63;
  const int wr = wave >> 1, wc = wave & 1;       // 2x2 wave grid, 64x64 each
  const int rowBase = blockIdx.y * 128;
  const int colBase = blockIdx.x * 128;
  const int c = lane & 15, q = lane >> 4;        // MFMA lane decomposition

  f32x4 acc[4][4];
#pragma unroll
  for (int mt = 0; mt < 4; ++mt)
#pragma unroll
    for (int nt = 0; nt < 4; ++nt) acc[mt][nt] = (f32x4){0.f, 0.f, 0.f, 0.f};

  // staging: thread -> (row sm, k-half sh); 16 fp32 per matrix per K-step
  const int sm = tid >> 1;
  const int sh = (tid & 1) * 16;
  const float* Ab = A + (size_t)(rowBase + sm) * E_DIM + sh;
  const float* Pb = P + (size_t)(colBase + sm) * E_DIM + sh;
  uint4* AsW = (uint4*)&As[sm * 40 + sh];
  uint4* PsW = (uint4*)&Ps[sm * 40 + sh];

  for (int kt = 0; kt < E_DIM; kt += BK) {
    float4 a0 = *(const float4*)(Ab + kt);
    float4 a1 = *(const float4*)(Ab + kt + 4);
    float4 a2 = *(const float4*)(Ab + kt + 8);
    float4 a3 = *(const float4*)(Ab + kt + 12);
    float4 p0 = *(const float4*)(Pb + kt);
    float4 p1 = *(const float4*)(Pb + kt + 4);
    float4 p2 = *(const float4*)(Pb + kt + 8);
    float4 p3 = *(const float4*)(Pb + kt + 12);
    uint4 av0 = {pk_bf16(a0.x, a0.y), pk_bf16(a0.z, a0.w),
                 pk_bf16(a1.x, a1.y), pk_bf16(a1.z, a1.w)};
    uint4 av1 = {pk_bf16(a2.x, a2.y), pk_bf16(a2.z, a2.w),
                 pk_bf16(a3.x, a3.y), pk_bf16(a3.z, a3.w)};
    uint4 pv0 = {pk_bf16(p0.x, p0.y), pk_bf16(p0.z, p0.w),
                 pk_bf16(p1.x, p1.y), pk_bf16(p1.z, p1.w)};
    uint4 pv1 = {pk_bf16(p2.x, p2.y), pk_bf16(p2.z, p2.w),
                 pk_bf16(p3.x, p3.y), pk_bf16(p3.z, p3.w)};
    AsW[0] = av0; AsW[1] = av1;
    PsW[0] = pv0; PsW[1] = pv1;
    __syncthreads();

    bf16x8 af[4], bfr[4];
#pragma unroll
    for (int mt = 0; mt < 4; ++mt)
      af[mt] = *(const bf16x8*)&As[(wr * 64 + mt * 16 + c) * 40 + q * 8];
#pragma unroll
    for (int nt = 0; nt < 4; ++nt)
      bfr[nt] = *(const bf16x8*)&Ps[(wc * 64 + nt * 16 + c) * 40 + q * 8];
#pragma unroll
    for (int mt = 0; mt < 4; ++mt)
#pragma unroll
      for (int nt = 0; nt < 4; ++nt)
        acc[mt][nt] = __builtin_amdgcn_mfma_f32_16x16x32_bf16(
            af[mt], bfr[nt], acc[mt][nt], 0, 0, 0);
    __syncthreads();
  }

  // Epilogue. C/D layout: col = lane&15 (=c), row = q*4 + reg.
  float inp_l[4];
#pragma unroll
  for (int nt = 0; nt < 4; ++nt)
    inp_l[nt] = inv_np[colBase + wc * 64 + nt * 16 + c];

#pragma unroll
  for (int mt = 0; mt < 4; ++mt) {
#pragma unroll
    for (int reg = 0; reg < 4; ++reg) {
      const int gi = rowBase + wr * 64 + mt * 16 + q * 4 + reg;
      float best = 3.4e38f;
      int bidx = 0;
#pragma unroll
      for (int nt = 0; nt < 4; ++nt) {
        const int gj = colBase + wc * 64 + nt * 16 + c;
        float v = acc[mt][nt][reg] * inp_l[nt];
        if (gj != gi && v < best) { best = v; bidx = gj; }
      }
#pragma unroll
      for (int off = 1; off < 16; off <<= 1) {
        float ov = __shfl_xor(best, off);
        int oi = __shfl_xor(bidx, off);
        if (ov < best) { best = ov; bidx = oi; }
      }
      if (c == 0) {
        unsigned long long pk =
            ((unsigned long long)f2mono(best) << 32) | (unsigned)bidx;
        atomicMin(&min64[gi], pk);
      }
    }
  }
}

// Kernel 3: exact fp32 recompute of an_i for the selected neighbor.
__global__ __launch_bounds__(256) void an_kernel(
    const float* __restrict__ A, const float* __restrict__ P,
    const float* __restrict__ inv_na, const float* __restrict__ inv_np,
    const unsigned long long* __restrict__ min64, float* __restrict__ an,
    int B) {
  const int row = blockIdx.x;
  const int t = threadIdx.x;
  // mask to [0,B): even a poisoned/unwritten min64 entry cannot fault
  const unsigned j = (unsigned)(min64[row] & 0xFFFFFFFFULL) & (unsigned)(B - 1);
  const float4* a4 = (const float4*)(A + (size_t)row * E_DIM);
  const float4* p4 = (const float4*)(P + (size_t)j * E_DIM);
  float s = 0.f;
  for (int ci = t; ci < E_DIM / 4; ci += 256) {
    float4 a = a4[ci];
    float4 p = p4[ci];
    s += a.x * p.x + a.y * p.y + a.z * p.z + a.w * p.w;
  }
#pragma unroll
  for (int off = 32; off > 0; off >>= 1) s += __shfl_down(s, off);
  __shared__ float red[4];
  const int wave = t >> 6, lane = t & 63;
  if (lane == 0) red[wave] = s;
  __syncthreads();
  if (t == 0) an[row] = (red[0] + red[1] + red[2] + red[3]) * inv_na[row] * inv_np[j];
}

// Kernel 4: loss_i = relu(1 + ap_i - an_i); out = mean.
__global__ __launch_bounds__(256) void loss_kernel(
    const float* __restrict__ ap, const float* __restrict__ an,
    float* __restrict__ out, int B) {
  const int t = threadIdx.x;
  float s = 0.f;
  for (int i = t; i < B; i += 256) {
    float l = 1.0f + ap[i] - an[i];
    s += (l > 0.f) ? l : 0.f;
  }
#pragma unroll
  for (int off = 32; off > 0; off >>= 1) s += __shfl_down(s, off);
  __shared__ float red[4];
  const int wave = t >> 6, lane = t & 63;
  if (lane == 0) red[wave] = s;
  __syncthreads();
  if (t == 0) out[0] = (red[0] + red[1] + red[2] + red[3]) / (float)B;
}

extern "C" void kernel_launch(void* const* d_in, const int* in_sizes, int n_in,
                              void* d_out, int out_size, void* d_ws, size_t ws_size,
                              hipStream_t stream) {
  const float* A = (const float*)d_in[0];  // anchor  [B][1024] fp32
  const float* P = (const float*)d_in[1];  // positive[B][1024] fp32
  const int B = in_sizes[0] / E_DIM;       // 8192

  // ws: inv_na[B] | inv_np[B] | ap[B] | an[B] | min64[B]  (~192 KB @ B=8192)
  float* inv_na = (float*)d_ws;
  float* inv_np = inv_na + B;
  float* ap = inv_np + B;
  float* an = ap + B;
  unsigned long long* min64 = (unsigned long long*)(an + B);

  norms_kernel<<<B, 256, 0, stream>>>(A, P, inv_na, inv_np, ap, min64);
  dim3 grid(B / 128, B / 128);
  simmin_mfma<<<grid, 256, 0, stream>>>(A, P, inv_np, min64);
  an_kernel<<<B, 256, 0, stream>>>(A, P, inv_na, inv_np, min64, an, B);
  loss_kernel<<<1, 256, 0, stream>>>(ap, an, (float*)d_out, B);
}

// Round 5
// 308.830 us; speedup vs baseline: 5.2149x; 1.3718x over previous
//
#include <hip/hip_runtime.h>

#define E_DIM 1024
#define NKB (E_DIM / 32)  // 32 k-chunks of 32

typedef __attribute__((ext_vector_type(8))) short bf16x8;
typedef __attribute__((ext_vector_type(4))) float f32x4;
typedef unsigned long long u64;

// ---- monotone float->uint so unsigned min == float min ----
__device__ __forceinline__ unsigned f2mono(float f) {
  unsigned u = __float_as_uint(f);
  return (u & 0x80000000u) ? ~u : (u | 0x80000000u);
}
// pack two fp32 into bf16x2 (truncation) with one v_perm_b32
__device__ __forceinline__ unsigned pk_bf16(float lo, float hi) {
  return __builtin_amdgcn_perm(__float_as_uint(hi), __float_as_uint(lo), 0x07060302u);
}
// async global->LDS, 16B per lane: lds image = lane-ordered copy of 1KB/wave
__device__ __forceinline__ void dma16(const void* g, void* l) {
  __builtin_amdgcn_global_load_lds(
      (const __attribute__((address_space(1))) unsigned*)g,
      (__attribute__((address_space(3))) unsigned*)l, 16, 0, 0);
}

// Kernel 1: per-row inverse norms, exact ap_i, init packed min array.
__global__ __launch_bounds__(256) void norms_kernel(
    const float* __restrict__ A, const float* __restrict__ P,
    float* __restrict__ inv_na, float* __restrict__ inv_np,
    float* __restrict__ ap, u64* __restrict__ min64) {
  const int row = blockIdx.x;
  const int t = threadIdx.x;
  const float4* a4 = (const float4*)(A + (size_t)row * E_DIM);
  const float4* p4 = (const float4*)(P + (size_t)row * E_DIM);
  float sa = 0.f, sp = 0.f, sab = 0.f;
  for (int c = t; c < E_DIM / 4; c += 256) {
    float4 a = a4[c];
    float4 p = p4[c];
    sa  += a.x * a.x + a.y * a.y + a.z * a.z + a.w * a.w;
    sp  += p.x * p.x + p.y * p.y + p.z * p.z + p.w * p.w;
    sab += a.x * p.x + a.y * p.y + a.z * p.z + a.w * p.w;
  }
#pragma unroll
  for (int off = 32; off > 0; off >>= 1) {
    sa  += __shfl_down(sa, off);
    sp  += __shfl_down(sp, off);
    sab += __shfl_down(sab, off);
  }
  __shared__ float red[4][3];
  const int wave = t >> 6, lane = t & 63;
  if (lane == 0) { red[wave][0] = sa; red[wave][1] = sp; red[wave][2] = sab; }
  __syncthreads();
  if (t == 0) {
    sa  = red[0][0] + red[1][0] + red[2][0] + red[3][0];
    sp  = red[0][1] + red[1][1] + red[2][1] + red[3][1];
    sab = red[0][2] + red[1][2] + red[2][2] + red[3][2];
    float ina = 1.0f / sqrtf(sa);
    float inp = 1.0f / sqrtf(sp);
    inv_na[row] = ina;
    inv_np[row] = inp;
    ap[row] = sab * ina * inp;
    min64[row] = 0xFFFFFFFFFFFFFFFFULL;  // +max packed
  }
}

// Kernel 1b: fp32 -> bf16 tiled convert. Chunk = (row_block rb of 128 rows,
// k-chunk kb of 32). 8KB chunk layout: shorts[(q*128 + row)*8 + j] where
// q = (k%32)/8, j = k%8 — exactly the MFMA A-operand fragment order, so the
// GEMM's DMA produces a directly-readable LDS image (no padding allowed by DMA).
__global__ __launch_bounds__(256) void convert_kernel(
    const float* __restrict__ X, unsigned short* __restrict__ Xt) {
  const int rb = blockIdx.x >> 5;
  const int kb = blockIdx.x & 31;
  const int t = threadIdx.x;
  const int row = t >> 1;
  const int half = t & 1;  // which 16-k half of the 32-k chunk
  const float* src = X + (size_t)(rb * 128 + row) * E_DIM + kb * 32 + half * 16;
  float4 v0 = ((const float4*)src)[0];
  float4 v1 = ((const float4*)src)[1];
  float4 v2 = ((const float4*)src)[2];
  float4 v3 = ((const float4*)src)[3];
  uint4 lo = {pk_bf16(v0.x, v0.y), pk_bf16(v0.z, v0.w),
              pk_bf16(v1.x, v1.y), pk_bf16(v1.z, v1.w)};  // q = 2*half
  uint4 hi = {pk_bf16(v2.x, v2.y), pk_bf16(v2.z, v2.w),
              pk_bf16(v3.x, v3.y), pk_bf16(v3.z, v3.w)};  // q = 2*half+1
  unsigned short* base = Xt + (size_t)blockIdx.x * 4096;
  *(uint4*)(base + ((2 * half + 0) * 128 + row) * 8) = lo;
  *(uint4*)(base + ((2 * half + 1) * 128 + row) * 8) = hi;
}

// Kernel 2: bf16 MFMA GEMM dot = A P^T from pre-tiled bf16 operands.
// 128x128 tile, 4 waves (2x2 of 64x64), 4x4 16x16x32 MFMA tiles per wave,
// BK=32, staging via global_load_lds width=16. Fused per-row min+argmin of
// dot*inv_np[col], j != i (row scale inv_na>0 can't change argmin; exact
// value repaired by an_kernel).
__global__ __launch_bounds__(256) void simmin_mfma2(
    const unsigned short* __restrict__ At, const unsigned short* __restrict__ Pt,
    const float* __restrict__ inv_np, u64* __restrict__ min64) {
  __shared__ __align__(16) short As[4096];  // 8KB chunk image
  __shared__ __align__(16) short Ps[4096];

  const int tid = threadIdx.x;
  const int wave = tid >> 6, lane = tid & 63;
  const int wr = wave >> 1, wc = wave & 1;
  const int rowBase = blockIdx.y * 128;
  const int colBase = blockIdx.x * 128;
  const int c = lane & 15, q = lane >> 4;

  f32x4 acc[4][4];
#pragma unroll
  for (int mt = 0; mt < 4; ++mt)
#pragma unroll
    for (int nt = 0; nt < 4; ++nt) acc[mt][nt] = (f32x4){0.f, 0.f, 0.f, 0.f};

  const char* Ab = (const char*)At + (size_t)blockIdx.y * (NKB * 8192);
  const char* Pb = (const char*)Pt + (size_t)blockIdx.x * (NKB * 8192);
  const int loff = wave * 2048;       // each wave stages 2KB of each 8KB chunk
  const int goff = loff + lane * 16;
  char* AsB = (char*)As;
  char* PsB = (char*)Ps;

  // fragment short-offsets: chunk[(q*128 + tile_row)*8 + j]
  const int aidx = (q * 128 + wr * 64 + c) * 8;
  const int bidx = (q * 128 + wc * 64 + c) * 8;

  for (int kt = 0; kt < NKB; ++kt) {
    const char* ca = Ab + (size_t)kt * 8192;
    const char* cp = Pb + (size_t)kt * 8192;
    dma16(ca + goff, AsB + loff);
    dma16(ca + goff + 1024, AsB + loff + 1024);
    dma16(cp + goff, PsB + loff);
    dma16(cp + goff + 1024, PsB + loff + 1024);
    __syncthreads();  // compiler emits vmcnt(0) drain before s_barrier

    bf16x8 af[4], bfr[4];
#pragma unroll
    for (int mt = 0; mt < 4; ++mt) af[mt] = *(const bf16x8*)&As[aidx + mt * 128];
#pragma unroll
    for (int nt = 0; nt < 4; ++nt) bfr[nt] = *(const bf16x8*)&Ps[bidx + nt * 128];
#pragma unroll
    for (int mt = 0; mt < 4; ++mt)
#pragma unroll
      for (int nt = 0; nt < 4; ++nt)
        acc[mt][nt] = __builtin_amdgcn_mfma_f32_16x16x32_bf16(
            af[mt], bfr[nt], acc[mt][nt], 0, 0, 0);
    __syncthreads();
  }

  // Epilogue. C/D layout: col = lane&15 (=c), row = q*4 + reg.
  float inp_l[4];
#pragma unroll
  for (int nt = 0; nt < 4; ++nt)
    inp_l[nt] = inv_np[colBase + wc * 64 + nt * 16 + c];

#pragma unroll
  for (int mt = 0; mt < 4; ++mt) {
#pragma unroll
    for (int reg = 0; reg < 4; ++reg) {
      const int gi = rowBase + wr * 64 + mt * 16 + q * 4 + reg;
      float best = 3.4e38f;
      int bidx2 = 0;
#pragma unroll
      for (int nt = 0; nt < 4; ++nt) {
        const int gj = colBase + wc * 64 + nt * 16 + c;
        float v = acc[mt][nt][reg] * inp_l[nt];
        if (gj != gi && v < best) { best = v; bidx2 = gj; }
      }
#pragma unroll
      for (int off = 1; off < 16; off <<= 1) {
        float ov = __shfl_xor(best, off);
        int oi = __shfl_xor(bidx2, off);
        if (ov < best) { best = ov; bidx2 = oi; }
      }
      if (c == 0) {
        u64 pk = ((u64)f2mono(best) << 32) | (unsigned)bidx2;
        atomicMin(&min64[gi], pk);
      }
    }
  }
}

// Fallback GEMM (round-3 proven): fp32 staging + in-loop convert. Used only
// if ws_size can't hold the bf16 pre-converted operands.
__global__ __launch_bounds__(256) void simmin_mfma(
    const float* __restrict__ A, const float* __restrict__ P,
    const float* __restrict__ inv_np, u64* __restrict__ min64) {
  __shared__ __align__(16) short As[128 * 40];
  __shared__ __align__(16) short Ps[128 * 40];

  const int tid = threadIdx.x;
  const int wave = tid >> 6, lane = tid & 63;
  const int wr = wave >> 1, wc = wave & 1;
  const int rowBase = blockIdx.y * 128;
  const int colBase = blockIdx.x * 128;
  const int c = lane & 15, q = lane >> 4;

  f32x4 acc[4][4];
#pragma unroll
  for (int mt = 0; mt < 4; ++mt)
#pragma unroll
    for (int nt = 0; nt < 4; ++nt) acc[mt][nt] = (f32x4){0.f, 0.f, 0.f, 0.f};

  const int sm = tid >> 1;
  const int sh = (tid & 1) * 16;
  const float* Ab = A + (size_t)(rowBase + sm) * E_DIM + sh;
  const float* Pb = P + (size_t)(colBase + sm) * E_DIM + sh;
  uint4* AsW = (uint4*)&As[sm * 40 + sh];
  uint4* PsW = (uint4*)&Ps[sm * 40 + sh];

  for (int kt = 0; kt < E_DIM; kt += 32) {
    float4 a0 = *(const float4*)(Ab + kt);
    float4 a1 = *(const float4*)(Ab + kt + 4);
    float4 a2 = *(const float4*)(Ab + kt + 8);
    float4 a3 = *(const float4*)(Ab + kt + 12);
    float4 p0 = *(const float4*)(Pb + kt);
    float4 p1 = *(const float4*)(Pb + kt + 4);
    float4 p2 = *(const float4*)(Pb + kt + 8);
    float4 p3 = *(const float4*)(Pb + kt + 12);
    uint4 av0 = {pk_bf16(a0.x, a0.y), pk_bf16(a0.z, a0.w),
                 pk_bf16(a1.x, a1.y), pk_bf16(a1.z, a1.w)};
    uint4 av1 = {pk_bf16(a2.x, a2.y), pk_bf16(a2.z, a2.w),
                 pk_bf16(a3.x, a3.y), pk_bf16(a3.z, a3.w)};
    uint4 pv0 = {pk_bf16(p0.x, p0.y), pk_bf16(p0.z, p0.w),
                 pk_bf16(p1.x, p1.y), pk_bf16(p1.z, p1.w)};
    uint4 pv1 = {pk_bf16(p2.x, p2.y), pk_bf16(p2.z, p2.w),
                 pk_bf16(p3.x, p3.y), pk_bf16(p3.z, p3.w)};
    AsW[0] = av0; AsW[1] = av1;
    PsW[0] = pv0; PsW[1] = pv1;
    __syncthreads();

    bf16x8 af[4], bfr[4];
#pragma unroll
    for (int mt = 0; mt < 4; ++mt)
      af[mt] = *(const bf16x8*)&As[(wr * 64 + mt * 16 + c) * 40 + q * 8];
#pragma unroll
    for (int nt = 0; nt < 4; ++nt)
      bfr[nt] = *(const bf16x8*)&Ps[(wc * 64 + nt * 16 + c) * 40 + q * 8];
#pragma unroll
    for (int mt = 0; mt < 4; ++mt)
#pragma unroll
      for (int nt = 0; nt < 4; ++nt)
        acc[mt][nt] = __builtin_amdgcn_mfma_f32_16x16x32_bf16(
            af[mt], bfr[nt], acc[mt][nt], 0, 0, 0);
    __syncthreads();
  }

  float inp_l[4];
#pragma unroll
  for (int nt = 0; nt < 4; ++nt)
    inp_l[nt] = inv_np[colBase + wc * 64 + nt * 16 + c];

#pragma unroll
  for (int mt = 0; mt < 4; ++mt) {
#pragma unroll
    for (int reg = 0; reg < 4; ++reg) {
      const int gi = rowBase + wr * 64 + mt * 16 + q * 4 + reg;
      float best = 3.4e38f;
      int bidx2 = 0;
#pragma unroll
      for (int nt = 0; nt < 4; ++nt) {
        const int gj = colBase + wc * 64 + nt * 16 + c;
        float v = acc[mt][nt][reg] * inp_l[nt];
        if (gj != gi && v < best) { best = v; bidx2 = gj; }
      }
#pragma unroll
      for (int off = 1; off < 16; off <<= 1) {
        float ov = __shfl_xor(best, off);
        int oi = __shfl_xor(bidx2, off);
        if (ov < best) { best = ov; bidx2 = oi; }
      }
      if (c == 0) {
        u64 pk = ((u64)f2mono(best) << 32) | (unsigned)bidx2;
        atomicMin(&min64[gi], pk);
      }
    }
  }
}

// Kernel 3: exact fp32 recompute of an_i for the selected neighbor.
__global__ __launch_bounds__(256) void an_kernel(
    const float* __restrict__ A, const float* __restrict__ P,
    const float* __restrict__ inv_na, const float* __restrict__ inv_np,
    const u64* __restrict__ min64, float* __restrict__ an, int B) {
  const int row = blockIdx.x;
  const int t = threadIdx.x;
  const unsigned j = (unsigned)(min64[row] & 0xFFFFFFFFULL) & (unsigned)(B - 1);
  const float4* a4 = (const float4*)(A + (size_t)row * E_DIM);
  const float4* p4 = (const float4*)(P + (size_t)j * E_DIM);
  float s = 0.f;
  for (int ci = t; ci < E_DIM / 4; ci += 256) {
    float4 a = a4[ci];
    float4 p = p4[ci];
    s += a.x * p.x + a.y * p.y + a.z * p.z + a.w * p.w;
  }
#pragma unroll
  for (int off = 32; off > 0; off >>= 1) s += __shfl_down(s, off);
  __shared__ float red[4];
  const int wave = t >> 6, lane = t & 63;
  if (lane == 0) red[wave] = s;
  __syncthreads();
  if (t == 0) an[row] = (red[0] + red[1] + red[2] + red[3]) * inv_na[row] * inv_np[j];
}

// Kernel 4: loss_i = relu(1 + ap_i - an_i); out = mean.
__global__ __launch_bounds__(256) void loss_kernel(
    const float* __restrict__ ap, const float* __restrict__ an,
    float* __restrict__ out, int B) {
  const int t = threadIdx.x;
  float s = 0.f;
  for (int i = t; i < B; i += 256) {
    float l = 1.0f + ap[i] - an[i];
    s += (l > 0.f) ? l : 0.f;
  }
#pragma unroll
  for (int off = 32; off > 0; off >>= 1) s += __shfl_down(s, off);
  __shared__ float red[4];
  const int wave = t >> 6, lane = t & 63;
  if (lane == 0) red[wave] = s;
  __syncthreads();
  if (t == 0) out[0] = (red[0] + red[1] + red[2] + red[3]) / (float)B;
}

extern "C" void kernel_launch(void* const* d_in, const int* in_sizes, int n_in,
                              void* d_out, int out_size, void* d_ws, size_t ws_size,
                              hipStream_t stream) {
  const float* A = (const float*)d_in[0];  // anchor  [B][1024] fp32
  const float* P = (const float*)d_in[1];  // positive[B][1024] fp32
  const int B = in_sizes[0] / E_DIM;       // 8192

  const size_t conv_elems = (size_t)B * E_DIM;      // per-matrix bf16 elems
  const size_t need = 2 * conv_elems * 2 + (size_t)B * 24 + 64;
  dim3 grid(B / 128, B / 128);

  if (ws_size >= need) {
    unsigned short* At = (unsigned short*)d_ws;
    unsigned short* Pt = At + conv_elems;
    u64* min64 = (u64*)(Pt + conv_elems);            // 8B-aligned (32MB offset)
    float* inv_na = (float*)(min64 + B);
    float* inv_np = inv_na + B;
    float* ap = inv_np + B;
    float* an = ap + B;

    norms_kernel<<<B, 256, 0, stream>>>(A, P, inv_na, inv_np, ap, min64);
    convert_kernel<<<(B / 128) * 32, 256, 0, stream>>>(A, At);
    convert_kernel<<<(B / 128) * 32, 256, 0, stream>>>(P, Pt);
    simmin_mfma2<<<grid, 256, 0, stream>>>(At, Pt, inv_np, min64);
    an_kernel<<<B, 256, 0, stream>>>(A, P, inv_na, inv_np, min64, an, B);
    loss_kernel<<<1, 256, 0, stream>>>(ap, an, (float*)d_out, B);
  } else {
    float* inv_na = (float*)d_ws;
    float* inv_np = inv_na + B;
    float* ap = inv_np + B;
    float* an = ap + B;
    u64* min64 = (u64*)(an + B);

    norms_kernel<<<B, 256, 0, stream>>>(A, P, inv_na, inv_np, ap, min64);
    simmin_mfma<<<grid, 256, 0, stream>>>(A, P, inv_np, min64);
    an_kernel<<<B, 256, 0, stream>>>(A, P, inv_na, inv_np, min64, an, B);
    loss_kernel<<<1, 256, 0, stream>>>(ap, an, (float*)d_out, B);
  }
}

// Round 6
// 280.129 us; speedup vs baseline: 5.7492x; 1.1025x over previous
//
#include <hip/hip_runtime.h>

#define E_DIM 1024
#define NKB (E_DIM / 32)  // 32 k-chunks of 32

typedef __attribute__((ext_vector_type(8))) short bf16x8;
typedef __attribute__((ext_vector_type(4))) float f32x4;
typedef unsigned long long u64;

// ---- monotone float->uint so unsigned min == float min ----
__device__ __forceinline__ unsigned f2mono(float f) {
  unsigned u = __float_as_uint(f);
  return (u & 0x80000000u) ? ~u : (u | 0x80000000u);
}
// pack two fp32 into bf16x2 (truncation) with one v_perm_b32
__device__ __forceinline__ unsigned pk_bf16(float lo, float hi) {
  return __builtin_amdgcn_perm(__float_as_uint(hi), __float_as_uint(lo), 0x07060302u);
}
// async global->LDS, 16B per lane: lds image = lane-ordered copy of 1KB/wave
__device__ __forceinline__ void dma16(const void* g, void* l) {
  __builtin_amdgcn_global_load_lds(
      (const __attribute__((address_space(1))) unsigned*)g,
      (__attribute__((address_space(3))) unsigned*)l, 16, 0, 0);
}

// Kernel 1: per-row inverse norms, exact ap_i, init packed min array.
__global__ __launch_bounds__(256) void norms_kernel(
    const float* __restrict__ A, const float* __restrict__ P,
    float* __restrict__ inv_na, float* __restrict__ inv_np,
    float* __restrict__ ap, u64* __restrict__ min64) {
  const int row = blockIdx.x;
  const int t = threadIdx.x;
  const float4* a4 = (const float4*)(A + (size_t)row * E_DIM);
  const float4* p4 = (const float4*)(P + (size_t)row * E_DIM);
  float sa = 0.f, sp = 0.f, sab = 0.f;
  for (int c = t; c < E_DIM / 4; c += 256) {
    float4 a = a4[c];
    float4 p = p4[c];
    sa  += a.x * a.x + a.y * a.y + a.z * a.z + a.w * a.w;
    sp  += p.x * p.x + p.y * p.y + p.z * p.z + p.w * p.w;
    sab += a.x * p.x + a.y * p.y + a.z * p.z + a.w * p.w;
  }
#pragma unroll
  for (int off = 32; off > 0; off >>= 1) {
    sa  += __shfl_down(sa, off);
    sp  += __shfl_down(sp, off);
    sab += __shfl_down(sab, off);
  }
  __shared__ float red[4][3];
  const int wave = t >> 6, lane = t & 63;
  if (lane == 0) { red[wave][0] = sa; red[wave][1] = sp; red[wave][2] = sab; }
  __syncthreads();
  if (t == 0) {
    sa  = red[0][0] + red[1][0] + red[2][0] + red[3][0];
    sp  = red[0][1] + red[1][1] + red[2][1] + red[3][1];
    sab = red[0][2] + red[1][2] + red[2][2] + red[3][2];
    float ina = 1.0f / sqrtf(sa);
    float inp = 1.0f / sqrtf(sp);
    inv_na[row] = ina;
    inv_np[row] = inp;
    ap[row] = sab * ina * inp;
    min64[row] = 0xFFFFFFFFFFFFFFFFULL;  // +max packed
  }
}

// Kernel 1b: fp32 -> bf16 tiled convert, BOTH matrices in one launch.
// Chunk = (row_block rb of 128 rows, k-chunk kb of 32). 8KB chunk layout:
// shorts[(q*128 + row)*8 + j], q=(k%32)/8, j=k%8 — the MFMA fragment order,
// so the GEMM's DMA produces a directly-readable LDS image.
__global__ __launch_bounds__(256) void convert_kernel(
    const float* __restrict__ A, const float* __restrict__ P,
    unsigned short* __restrict__ At, unsigned short* __restrict__ Pt,
    int nchunk) {
  const int b = blockIdx.x;
  const float* X = (b < nchunk) ? A : P;
  unsigned short* Xt = (b < nchunk) ? At : Pt;
  const int cb = (b < nchunk) ? b : b - nchunk;
  const int rb = cb >> 5;
  const int kb = cb & 31;
  const int t = threadIdx.x;
  const int row = t >> 1;
  const int half = t & 1;  // which 16-k half of the 32-k chunk
  const float* src = X + (size_t)(rb * 128 + row) * E_DIM + kb * 32 + half * 16;
  float4 v0 = ((const float4*)src)[0];
  float4 v1 = ((const float4*)src)[1];
  float4 v2 = ((const float4*)src)[2];
  float4 v3 = ((const float4*)src)[3];
  uint4 lo = {pk_bf16(v0.x, v0.y), pk_bf16(v0.z, v0.w),
              pk_bf16(v1.x, v1.y), pk_bf16(v1.z, v1.w)};  // q = 2*half
  uint4 hi = {pk_bf16(v2.x, v2.y), pk_bf16(v2.z, v2.w),
              pk_bf16(v3.x, v3.y), pk_bf16(v3.z, v3.w)};  // q = 2*half+1
  unsigned short* base = Xt + (size_t)cb * 4096;
  *(uint4*)(base + ((2 * half + 0) * 128 + row) * 8) = lo;
  *(uint4*)(base + ((2 * half + 1) * 128 + row) * 8) = hi;
}

// Kernel 2: bf16 MFMA GEMM dot = A P^T from pre-tiled bf16 operands.
// 128x128 tile, 4 waves (2x2 of 64x64), BK=64 (two 8KB chunks per matrix per
// iter -> half the barrier drains of BK=32), staging via global_load_lds
// width=16. XCD-aware 8x8 supertile swizzle: with round-robin lid%8 -> XCD,
// the 64 blocks co-resident on one XCD share 8 row-slabs + 8 col-slabs
// (16 x 256KB = 4MB = one XCD's L2). Fused per-row min+argmin of
// dot*inv_np[col], j != i (row scale inv_na>0 can't change argmin; exact
// value repaired by an_kernel).
__global__ __launch_bounds__(256) void simmin_mfma3(
    const unsigned short* __restrict__ At, const unsigned short* __restrict__ Pt,
    const float* __restrict__ inv_np, u64* __restrict__ min64, int nb) {
  __shared__ __align__(16) short As[8192];  // 16KB: two 8KB chunk images
  __shared__ __align__(16) short Ps[8192];

  const int lid = blockIdx.x;
  int by, bx;
  if (nb == 64) {  // B=8192: 8x8 supertiles of 8x8 blocks, one supertile/XCD
    const int xcd = lid & 7;
    const int s = lid >> 3;       // per-XCD dispatch sequence
    const int st = xcd * 8 + (s >> 6);  // global supertile [0,64)
    const int u = s & 63;
    by = (st >> 3) * 8 + (u >> 3);
    bx = (st & 7) * 8 + (u & 7);
  } else {
    by = lid / nb;
    bx = lid % nb;
  }

  const int tid = threadIdx.x;
  const int wave = tid >> 6, lane = tid & 63;
  const int wr = wave >> 1, wc = wave & 1;
  const int rowBase = by * 128;
  const int colBase = bx * 128;
  const int c = lane & 15, q = lane >> 4;

  f32x4 acc[4][4];
#pragma unroll
  for (int mt = 0; mt < 4; ++mt)
#pragma unroll
    for (int nt = 0; nt < 4; ++nt) acc[mt][nt] = (f32x4){0.f, 0.f, 0.f, 0.f};

  const char* Ab = (const char*)At + (size_t)by * (NKB * 8192);
  const char* Pb = (const char*)Pt + (size_t)bx * (NKB * 8192);
  const int loff = wave * 2048;       // each wave stages 2KB of each 8KB chunk
  const int goff = loff + lane * 16;
  char* AsB = (char*)As;
  char* PsB = (char*)Ps;

  // fragment short-offsets within an 8KB chunk: [(q*128 + tile_row)*8 + j]
  const int aidx = (q * 128 + wr * 64 + c) * 8;
  const int bidx = (q * 128 + wc * 64 + c) * 8;

  for (int kt = 0; kt < NKB / 2; ++kt) {  // 16 iters of BK=64
    const char* ca = Ab + (size_t)kt * 16384;
    const char* cp = Pb + (size_t)kt * 16384;
    dma16(ca + goff, AsB + loff);
    dma16(ca + goff + 1024, AsB + loff + 1024);
    dma16(ca + 8192 + goff, AsB + 8192 + loff);
    dma16(ca + 8192 + goff + 1024, AsB + 8192 + loff + 1024);
    dma16(cp + goff, PsB + loff);
    dma16(cp + goff + 1024, PsB + loff + 1024);
    dma16(cp + 8192 + goff, PsB + 8192 + loff);
    dma16(cp + 8192 + goff + 1024, PsB + 8192 + loff + 1024);
    __syncthreads();  // vmcnt(0) drain + barrier

#pragma unroll
    for (int kk = 0; kk < 2; ++kk) {
      bf16x8 af[4], bfr[4];
#pragma unroll
      for (int mt = 0; mt < 4; ++mt)
        af[mt] = *(const bf16x8*)&As[kk * 4096 + aidx + mt * 128];
#pragma unroll
      for (int nt = 0; nt < 4; ++nt)
        bfr[nt] = *(const bf16x8*)&Ps[kk * 4096 + bidx + nt * 128];
#pragma unroll
      for (int mt = 0; mt < 4; ++mt)
#pragma unroll
        for (int nt = 0; nt < 4; ++nt)
          acc[mt][nt] = __builtin_amdgcn_mfma_f32_16x16x32_bf16(
              af[mt], bfr[nt], acc[mt][nt], 0, 0, 0);
    }
    __syncthreads();
  }

  // Epilogue. C/D layout: col = lane&15 (=c), row = q*4 + reg.
  float inp_l[4];
#pragma unroll
  for (int nt = 0; nt < 4; ++nt)
    inp_l[nt] = inv_np[colBase + wc * 64 + nt * 16 + c];

#pragma unroll
  for (int mt = 0; mt < 4; ++mt) {
#pragma unroll
    for (int reg = 0; reg < 4; ++reg) {
      const int gi = rowBase + wr * 64 + mt * 16 + q * 4 + reg;
      float best = 3.4e38f;
      int bidx2 = 0;
#pragma unroll
      for (int nt = 0; nt < 4; ++nt) {
        const int gj = colBase + wc * 64 + nt * 16 + c;
        float v = acc[mt][nt][reg] * inp_l[nt];
        if (gj != gi && v < best) { best = v; bidx2 = gj; }
      }
#pragma unroll
      for (int off = 1; off < 16; off <<= 1) {
        float ov = __shfl_xor(best, off);
        int oi = __shfl_xor(bidx2, off);
        if (ov < best) { best = ov; bidx2 = oi; }
      }
      if (c == 0) {
        u64 pk = ((u64)f2mono(best) << 32) | (unsigned)bidx2;
        atomicMin(&min64[gi], pk);
      }
    }
  }
}

// Fallback GEMM (round-3 proven): fp32 staging + in-loop convert. Used only
// if ws_size can't hold the bf16 pre-converted operands.
__global__ __launch_bounds__(256) void simmin_mfma(
    const float* __restrict__ A, const float* __restrict__ P,
    const float* __restrict__ inv_np, u64* __restrict__ min64) {
  __shared__ __align__(16) short As[128 * 40];
  __shared__ __align__(16) short Ps[128 * 40];

  const int tid = threadIdx.x;
  const int wave = tid >> 6, lane = tid & 63;
  const int wr = wave >> 1, wc = wave & 1;
  const int rowBase = blockIdx.y * 128;
  const int colBase = blockIdx.x * 128;
  const int c = lane & 15, q = lane >> 4;

  f32x4 acc[4][4];
#pragma unroll
  for (int mt = 0; mt < 4; ++mt)
#pragma unroll
    for (int nt = 0; nt < 4; ++nt) acc[mt][nt] = (f32x4){0.f, 0.f, 0.f, 0.f};

  const int sm = tid >> 1;
  const int sh = (tid & 1) * 16;
  const float* Ab = A + (size_t)(rowBase + sm) * E_DIM + sh;
  const float* Pb = P + (size_t)(colBase + sm) * E_DIM + sh;
  uint4* AsW = (uint4*)&As[sm * 40 + sh];
  uint4* PsW = (uint4*)&Ps[sm * 40 + sh];

  for (int kt = 0; kt < E_DIM; kt += 32) {
    float4 a0 = *(const float4*)(Ab + kt);
    float4 a1 = *(const float4*)(Ab + kt + 4);
    float4 a2 = *(const float4*)(Ab + kt + 8);
    float4 a3 = *(const float4*)(Ab + kt + 12);
    float4 p0 = *(const float4*)(Pb + kt);
    float4 p1 = *(const float4*)(Pb + kt + 4);
    float4 p2 = *(const float4*)(Pb + kt + 8);
    float4 p3 = *(const float4*)(Pb + kt + 12);
    uint4 av0 = {pk_bf16(a0.x, a0.y), pk_bf16(a0.z, a0.w),
                 pk_bf16(a1.x, a1.y), pk_bf16(a1.z, a1.w)};
    uint4 av1 = {pk_bf16(a2.x, a2.y), pk_bf16(a2.z, a2.w),
                 pk_bf16(a3.x, a3.y), pk_bf16(a3.z, a3.w)};
    uint4 pv0 = {pk_bf16(p0.x, p0.y), pk_bf16(p0.z, p0.w),
                 pk_bf16(p1.x, p1.y), pk_bf16(p1.z, p1.w)};
    uint4 pv1 = {pk_bf16(p2.x, p2.y), pk_bf16(p2.z, p2.w),
                 pk_bf16(p3.x, p3.y), pk_bf16(p3.z, p3.w)};
    AsW[0] = av0; AsW[1] = av1;
    PsW[0] = pv0; PsW[1] = pv1;
    __syncthreads();

    bf16x8 af[4], bfr[4];
#pragma unroll
    for (int mt = 0; mt < 4; ++mt)
      af[mt] = *(const bf16x8*)&As[(wr * 64 + mt * 16 + c) * 40 + q * 8];
#pragma unroll
    for (int nt = 0; nt < 4; ++nt)
      bfr[nt] = *(const bf16x8*)&Ps[(wc * 64 + nt * 16 + c) * 40 + q * 8];
#pragma unroll
    for (int mt = 0; mt < 4; ++mt)
#pragma unroll
      for (int nt = 0; nt < 4; ++nt)
        acc[mt][nt] = __builtin_amdgcn_mfma_f32_16x16x32_bf16(
            af[mt], bfr[nt], acc[mt][nt], 0, 0, 0);
    __syncthreads();
  }

  float inp_l[4];
#pragma unroll
  for (int nt = 0; nt < 4; ++nt)
    inp_l[nt] = inv_np[colBase + wc * 64 + nt * 16 + c];

#pragma unroll
  for (int mt = 0; mt < 4; ++mt) {
#pragma unroll
    for (int reg = 0; reg < 4; ++reg) {
      const int gi = rowBase + wr * 64 + mt * 16 + q * 4 + reg;
      float best = 3.4e38f;
      int bidx2 = 0;
#pragma unroll
      for (int nt = 0; nt < 4; ++nt) {
        const int gj = colBase + wc * 64 + nt * 16 + c;
        float v = acc[mt][nt][reg] * inp_l[nt];
        if (gj != gi && v < best) { best = v; bidx2 = gj; }
      }
#pragma unroll
      for (int off = 1; off < 16; off <<= 1) {
        float ov = __shfl_xor(best, off);
        int oi = __shfl_xor(bidx2, off);
        if (ov < best) { best = ov; bidx2 = oi; }
      }
      if (c == 0) {
        u64 pk = ((u64)f2mono(best) << 32) | (unsigned)bidx2;
        atomicMin(&min64[gi], pk);
      }
    }
  }
}

// Kernel 3: exact fp32 recompute of an_i for the selected neighbor.
__global__ __launch_bounds__(256) void an_kernel(
    const float* __restrict__ A, const float* __restrict__ P,
    const float* __restrict__ inv_na, const float* __restrict__ inv_np,
    const u64* __restrict__ min64, float* __restrict__ an, int B) {
  const int row = blockIdx.x;
  const int t = threadIdx.x;
  const unsigned j = (unsigned)(min64[row] & 0xFFFFFFFFULL) & (unsigned)(B - 1);
  const float4* a4 = (const float4*)(A + (size_t)row * E_DIM);
  const float4* p4 = (const float4*)(P + (size_t)j * E_DIM);
  float s = 0.f;
  for (int ci = t; ci < E_DIM / 4; ci += 256) {
    float4 a = a4[ci];
    float4 p = p4[ci];
    s += a.x * p.x + a.y * p.y + a.z * p.z + a.w * p.w;
  }
#pragma unroll
  for (int off = 32; off > 0; off >>= 1) s += __shfl_down(s, off);
  __shared__ float red[4];
  const int wave = t >> 6, lane = t & 63;
  if (lane == 0) red[wave] = s;
  __syncthreads();
  if (t == 0) an[row] = (red[0] + red[1] + red[2] + red[3]) * inv_na[row] * inv_np[j];
}

// Kernel 4: loss_i = relu(1 + ap_i - an_i); out = mean.
__global__ __launch_bounds__(256) void loss_kernel(
    const float* __restrict__ ap, const float* __restrict__ an,
    float* __restrict__ out, int B) {
  const int t = threadIdx.x;
  float s = 0.f;
  for (int i = t; i < B; i += 256) {
    float l = 1.0f + ap[i] - an[i];
    s += (l > 0.f) ? l : 0.f;
  }
#pragma unroll
  for (int off = 32; off > 0; off >>= 1) s += __shfl_down(s, off);
  __shared__ float red[4];
  const int wave = t >> 6, lane = t & 63;
  if (lane == 0) red[wave] = s;
  __syncthreads();
  if (t == 0) out[0] = (red[0] + red[1] + red[2] + red[3]) / (float)B;
}

extern "C" void kernel_launch(void* const* d_in, const int* in_sizes, int n_in,
                              void* d_out, int out_size, void* d_ws, size_t ws_size,
                              hipStream_t stream) {
  const float* A = (const float*)d_in[0];  // anchor  [B][1024] fp32
  const float* P = (const float*)d_in[1];  // positive[B][1024] fp32
  const int B = in_sizes[0] / E_DIM;       // 8192

  const size_t conv_elems = (size_t)B * E_DIM;      // per-matrix bf16 elems
  const size_t need = 2 * conv_elems * 2 + (size_t)B * 24 + 64;
  const int nb = B / 128;

  if (ws_size >= need) {
    unsigned short* At = (unsigned short*)d_ws;
    unsigned short* Pt = At + conv_elems;
    u64* min64 = (u64*)(Pt + conv_elems);            // 8B-aligned (32MB offset)
    float* inv_na = (float*)(min64 + B);
    float* inv_np = inv_na + B;
    float* ap = inv_np + B;
    float* an = ap + B;
    const int nchunk = nb * 32;

    norms_kernel<<<B, 256, 0, stream>>>(A, P, inv_na, inv_np, ap, min64);
    convert_kernel<<<2 * nchunk, 256, 0, stream>>>(A, P, At, Pt, nchunk);
    simmin_mfma3<<<nb * nb, 256, 0, stream>>>(At, Pt, inv_np, min64, nb);
    an_kernel<<<B, 256, 0, stream>>>(A, P, inv_na, inv_np, min64, an, B);
    loss_kernel<<<1, 256, 0, stream>>>(ap, an, (float*)d_out, B);
  } else {
    float* inv_na = (float*)d_ws;
    float* inv_np = inv_na + B;
    float* ap = inv_np + B;
    float* an = ap + B;
    u64* min64 = (u64*)(an + B);
    dim3 grid(nb, nb);

    norms_kernel<<<B, 256, 0, stream>>>(A, P, inv_na, inv_np, ap, min64);
    simmin_mfma<<<grid, 256, 0, stream>>>(A, P, inv_np, min64);
    an_kernel<<<B, 256, 0, stream>>>(A, P, inv_na, inv_np, min64, an, B);
    loss_kernel<<<1, 256, 0, stream>>>(ap, an, (float*)d_out, B);
  }
}